// Round 15
// baseline (792.489 us; speedup 1.0000x reference)
//
#include <hip/hip_runtime.h>
#include <hip/hip_cooperative_groups.h>
#include <hip/hip_bf16.h>
#include <math.h>

namespace cg = cooperative_groups;

// ---------------------------------------------------------------------------
// Cooperative mega-kernel (single dispatch) with automatic fallback to the
// proven multi-kernel pipeline if cooperative launch is unavailable/fails.
// Pipeline: zero+wcvt -> count -> scan1 -> scan23 -> {csr || gemm1} -> agg1
//           -> gemm2 -> agg2 -> pool_partial -> pool+LSTM+heads
// GEMMs bf16 MFMA (f32 accum); gather buffer fp8-e4m3; h bf16; reductions f32.
// ---------------------------------------------------------------------------

#define POOL_SUB 32

#if __has_builtin(__builtin_amdgcn_cvt_pk_f32_fp8) && __has_builtin(__builtin_amdgcn_cvt_pk_fp8_f32)
#define USE_FP8 1
#else
#define USE_FP8 0
#endif

typedef __attribute__((ext_vector_type(8))) short bf16x8;
typedef __attribute__((ext_vector_type(4))) float f32x4;
typedef __attribute__((ext_vector_type(2))) float f32x2;

static __device__ __forceinline__ unsigned short f2bf(float f) {
    union { float f; unsigned int u; } v; v.f = f;
    unsigned int u = v.u;
    unsigned int r = u + 0x7FFFu + ((u >> 16) & 1u);  // RNE
    return (unsigned short)(r >> 16);
}
static __device__ __forceinline__ unsigned int pack2bf(float lo, float hi) {
    return (unsigned int)f2bf(lo) | ((unsigned int)f2bf(hi) << 16);
}
static __device__ __forceinline__ float bflo(unsigned int v) {
    union { unsigned int u; float f; } w; w.u = v << 16; return w.f;
}
static __device__ __forceinline__ float bfhi(unsigned int v) {
    union { unsigned int u; float f; } w; w.u = v & 0xFFFF0000u; return w.f;
}
static __device__ __forceinline__ bf16x8 f8_to_bf(float4 f0, float4 f1) {
    union { unsigned int u[4]; bf16x8 v; } r;
    r.u[0] = pack2bf(f0.x, f0.y);
    r.u[1] = pack2bf(f0.z, f0.w);
    r.u[2] = pack2bf(f1.x, f1.y);
    r.u[3] = pack2bf(f1.z, f1.w);
    return r.v;
}
#if USE_FP8
static __device__ __forceinline__ unsigned char f2fp8(float f) {
    return (unsigned char)(__builtin_amdgcn_cvt_pk_fp8_f32(f, f, 0, false) & 0xFF);
}
#endif

struct MegaArgs {
    const float* x;
    const int* src; const int* dst; const int* batch;
    const float* W1; const float* b1; const float* W2; const float* b2;
    const float* W_ih; const float* b_ih; const float* b_hh;
    const float* Wm; const float* bm; const float* Wv; const float* bv;
    float* out;
    void* gbuf;            // fp8 (or bf16 fallback) gather buffer
    unsigned int* hbuf;    // bf16 h buffer
    int* deg; int* cursor; int* rowptr; int* bsums; int* csr;
    float* dinv;
    unsigned short* Wt1; unsigned short* Wt2;
    float* partial;
    int N, E, nchunks, gb, ab;
};

#if USE_FP8
#define STORE_G(p, row, col, val) ((unsigned char*)(p))[(size_t)(row) * 128 + (col)] = f2fp8(val)
#else
#define STORE_G(p, row, col, val) ((unsigned short*)(p))[(size_t)(row) * 128 + (col)] = f2bf(val)
#endif

// ---- shared device phases ------------------------------------------------

__device__ __forceinline__ void gemm_tile_f32a(int t, const MegaArgs& a) {
    int tid = threadIdx.x;
    int l = tid & 63, wid = tid >> 6;
    int rowbase = t * 64 + wid * 16;
    int lc = l & 15, kq = l >> 4;
    int n = a.N;
    int arow = rowbase + lc; if (arow > n - 1) arow = n - 1;
    const float* Ap = a.x + (size_t)arow * 128 + kq * 8;
    const unsigned short* Wp = a.Wt1 + (size_t)lc * 128 + kq * 8;
    f32x4 acc[8];
#pragma unroll
    for (int c = 0; c < 8; ++c) acc[c] = (f32x4){0.f, 0.f, 0.f, 0.f};
#pragma unroll
    for (int ks = 0; ks < 4; ++ks) {
        float4 f0 = *(const float4*)(Ap + ks * 32);
        float4 f1 = *(const float4*)(Ap + ks * 32 + 4);
        bf16x8 av = f8_to_bf(f0, f1);
#pragma unroll
        for (int c = 0; c < 8; ++c) {
            bf16x8 bv = *(const bf16x8*)(Wp + c * 2048 + ks * 32);
            acc[c] = __builtin_amdgcn_mfma_f32_16x16x32_bf16(av, bv, acc[c], 0, 0, 0);
        }
    }
    int r0 = kq * 4;
#pragma unroll
    for (int r = 0; r < 4; ++r) {
        int orow = rowbase + r0 + r;
        if (orow < n) {
            float s = a.dinv[orow];
#pragma unroll
            for (int c = 0; c < 8; ++c) STORE_G(a.gbuf, orow, c * 16 + lc, acc[c][r] * s);
        }
    }
}

__device__ __forceinline__ void gemm_tile_h(int t, const MegaArgs& a) {
    int tid = threadIdx.x;
    int l = tid & 63, wid = tid >> 6;
    int rowbase = t * 64 + wid * 16;
    int lc = l & 15, kq = l >> 4;
    int n = a.N;
    int arow = rowbase + lc; if (arow > n - 1) arow = n - 1;
    const unsigned short* Ap = (const unsigned short*)a.hbuf + (size_t)arow * 128 + kq * 8;
    const unsigned short* Wp = a.Wt2 + (size_t)lc * 128 + kq * 8;
    f32x4 acc[8];
#pragma unroll
    for (int c = 0; c < 8; ++c) acc[c] = (f32x4){0.f, 0.f, 0.f, 0.f};
#pragma unroll
    for (int ks = 0; ks < 4; ++ks) {
        bf16x8 av = *(const bf16x8*)(Ap + ks * 32);
#pragma unroll
        for (int c = 0; c < 8; ++c) {
            bf16x8 bv = *(const bf16x8*)(Wp + c * 2048 + ks * 32);
            acc[c] = __builtin_amdgcn_mfma_f32_16x16x32_bf16(av, bv, acc[c], 0, 0, 0);
        }
    }
    int r0 = kq * 4;
#pragma unroll
    for (int r = 0; r < 4; ++r) {
        int orow = rowbase + r0 + r;
        if (orow < n) {
            float s = a.dinv[orow];
#pragma unroll
            for (int c = 0; c < 8; ++c) STORE_G(a.gbuf, orow, c * 16 + lc, acc[c][r] * s);
        }
    }
}

__device__ __forceinline__ void agg_group(int grp, const float* bias, const MegaArgs& a) {
    int lane = threadIdx.x & 63;
    int wid = threadIdx.x >> 6;
    int node = grp * 4 + wid;
    if (node >= a.N) return;  // no barriers below
    int beg = a.rowptr[node], end = a.rowptr[node + 1];
#if USE_FP8
    const uint2* g2 = (const uint2*)a.gbuf;  // row = 16 uint2
    int li = lane & 15, quad = lane >> 4;
    float a0 = 0.f, a1 = 0.f, a2 = 0.f, a3 = 0.f;
    float a4 = 0.f, a5 = 0.f, a6 = 0.f, a7 = 0.f;
    int e = beg;
    for (; e + 4 <= end; e += 4) {
        uint2 v = g2[(size_t)a.csr[e + quad] * 16 + li];
        f32x2 p0 = __builtin_amdgcn_cvt_pk_f32_fp8(v.x, false);
        f32x2 p1 = __builtin_amdgcn_cvt_pk_f32_fp8(v.x, true);
        f32x2 p2 = __builtin_amdgcn_cvt_pk_f32_fp8(v.y, false);
        f32x2 p3 = __builtin_amdgcn_cvt_pk_f32_fp8(v.y, true);
        a0 += p0.x; a1 += p0.y; a2 += p1.x; a3 += p1.y;
        a4 += p2.x; a5 += p2.y; a6 += p3.x; a7 += p3.y;
    }
    if (e + quad < end) {
        uint2 v = g2[(size_t)a.csr[e + quad] * 16 + li];
        f32x2 p0 = __builtin_amdgcn_cvt_pk_f32_fp8(v.x, false);
        f32x2 p1 = __builtin_amdgcn_cvt_pk_f32_fp8(v.x, true);
        f32x2 p2 = __builtin_amdgcn_cvt_pk_f32_fp8(v.y, false);
        f32x2 p3 = __builtin_amdgcn_cvt_pk_f32_fp8(v.y, true);
        a0 += p0.x; a1 += p0.y; a2 += p1.x; a3 += p1.y;
        a4 += p2.x; a5 += p2.y; a6 += p3.x; a7 += p3.y;
    }
    a0 += __shfl_xor(a0, 16, 64); a0 += __shfl_xor(a0, 32, 64);
    a1 += __shfl_xor(a1, 16, 64); a1 += __shfl_xor(a1, 32, 64);
    a2 += __shfl_xor(a2, 16, 64); a2 += __shfl_xor(a2, 32, 64);
    a3 += __shfl_xor(a3, 16, 64); a3 += __shfl_xor(a3, 32, 64);
    a4 += __shfl_xor(a4, 16, 64); a4 += __shfl_xor(a4, 32, 64);
    a5 += __shfl_xor(a5, 16, 64); a5 += __shfl_xor(a5, 32, 64);
    a6 += __shfl_xor(a6, 16, 64); a6 += __shfl_xor(a6, 32, 64);
    a7 += __shfl_xor(a7, 16, 64); a7 += __shfl_xor(a7, 32, 64);
    if (quad == 0) {
        uint2 sv = g2[(size_t)node * 16 + li];  // self loop
        f32x2 s0 = __builtin_amdgcn_cvt_pk_f32_fp8(sv.x, false);
        f32x2 s1 = __builtin_amdgcn_cvt_pk_f32_fp8(sv.x, true);
        f32x2 s2 = __builtin_amdgcn_cvt_pk_f32_fp8(sv.y, false);
        f32x2 s3 = __builtin_amdgcn_cvt_pk_f32_fp8(sv.y, true);
        float dv = a.dinv[node];
        float4 bl = ((const float4*)bias)[li * 2];
        float4 bh = ((const float4*)bias)[li * 2 + 1];
        float r0 = fmaxf(dv * (a0 + s0.x) + bl.x, 0.f);
        float r1 = fmaxf(dv * (a1 + s0.y) + bl.y, 0.f);
        float r2 = fmaxf(dv * (a2 + s1.x) + bl.z, 0.f);
        float r3 = fmaxf(dv * (a3 + s1.y) + bl.w, 0.f);
        float r4 = fmaxf(dv * (a4 + s2.x) + bh.x, 0.f);
        float r5 = fmaxf(dv * (a5 + s2.y) + bh.y, 0.f);
        float r6 = fmaxf(dv * (a6 + s3.x) + bh.z, 0.f);
        float r7 = fmaxf(dv * (a7 + s3.y) + bh.w, 0.f);
        uint4 o;
        o.x = pack2bf(r0, r1); o.y = pack2bf(r2, r3);
        o.z = pack2bf(r4, r5); o.w = pack2bf(r6, r7);
        ((uint4*)a.hbuf)[(size_t)node * 16 + li] = o;
    }
#else
    const uint2* g2 = (const uint2*)a.gbuf;  // bf16 rows, 32 uint2
    int li = lane & 31, pair = lane >> 5;
    float a0 = 0.f, a1 = 0.f, a2 = 0.f, a3 = 0.f;
    int e = beg;
    for (; e + 2 <= end; e += 2) {
        uint2 v = g2[(size_t)a.csr[e + pair] * 32 + li];
        a0 += bflo(v.x); a1 += bfhi(v.x);
        a2 += bflo(v.y); a3 += bfhi(v.y);
    }
    if (e + pair < end) {
        uint2 v = g2[(size_t)a.csr[e + pair] * 32 + li];
        a0 += bflo(v.x); a1 += bfhi(v.x);
        a2 += bflo(v.y); a3 += bfhi(v.y);
    }
    a0 += __shfl_xor(a0, 32, 64);
    a1 += __shfl_xor(a1, 32, 64);
    a2 += __shfl_xor(a2, 32, 64);
    a3 += __shfl_xor(a3, 32, 64);
    if (pair == 0) {
        uint2 sv = g2[(size_t)node * 32 + li];
        float dv = a.dinv[node];
        float4 b = ((const float4*)bias)[li];
        float r0 = fmaxf(dv * (a0 + bflo(sv.x)) + b.x, 0.f);
        float r1 = fmaxf(dv * (a1 + bfhi(sv.x)) + b.y, 0.f);
        float r2 = fmaxf(dv * (a2 + bflo(sv.y)) + b.z, 0.f);
        float r3 = fmaxf(dv * (a3 + bfhi(sv.y)) + b.w, 0.f);
        ((uint2*)a.hbuf)[(size_t)node * 32 + li] = make_uint2(pack2bf(r0, r1), pack2bf(r2, r3));
    }
#endif
}

__device__ __forceinline__ void pool_partial_unit(int unit, int t, const MegaArgs& a) {
    int g = unit / POOL_SUB;
    int sub = unit % POOL_SUB;
    int n = a.N;
    int lo = 0, hi = n;
    while (lo < hi) { int mid = (lo + hi) >> 1; if (a.batch[mid] < g) lo = mid + 1; else hi = mid; }
    int start = lo;
    hi = n;
    while (lo < hi) { int mid = (lo + hi) >> 1; if (a.batch[mid] < g + 1) lo = mid + 1; else hi = mid; }
    int end = lo;
    int len = end - start;
    int b0 = start + (int)((long long)len * sub / POOL_SUB);
    int b1 = start + (int)((long long)len * (sub + 1) / POOL_SUB);
    float ax = 0.f, ay = 0.f;
    int i = b0;
    for (; i + 4 <= b1; i += 4) {
        unsigned int v0 = a.hbuf[(size_t)(i + 0) * 64 + t];
        unsigned int v1 = a.hbuf[(size_t)(i + 1) * 64 + t];
        unsigned int v2 = a.hbuf[(size_t)(i + 2) * 64 + t];
        unsigned int v3 = a.hbuf[(size_t)(i + 3) * 64 + t];
        ax += bflo(v0) + bflo(v1) + bflo(v2) + bflo(v3);
        ay += bfhi(v0) + bfhi(v1) + bfhi(v2) + bfhi(v3);
    }
    for (; i < b1; ++i) {
        unsigned int v0 = a.hbuf[(size_t)i * 64 + t];
        ax += bflo(v0);
        ay += bfhi(v0);
    }
    a.partial[(size_t)unit * 128 + 2 * t]     = ax;
    a.partial[(size_t)unit * 128 + 2 * t + 1] = ay;
}

// pool finish + LSTM + heads for graph g (256-thread block). shraw >= 2560 B.
__device__ __forceinline__ void pool_lstm_graph(int g, float* shraw, const MegaArgs& a) {
    float* p = shraw;
    float* redm = p + 128;
    float* redv = redm + 256;
    int tid = threadIdx.x;
    if (tid < 128) {
        int lo = 0, hi = a.N;
        while (lo < hi) { int mid = (lo + hi) >> 1; if (a.batch[mid] < g) lo = mid + 1; else hi = mid; }
        int start = lo;
        hi = a.N;
        while (lo < hi) { int mid = (lo + hi) >> 1; if (a.batch[mid] < g + 1) lo = mid + 1; else hi = mid; }
        int end = lo;
        float acc = 0.f;
#pragma unroll
        for (int s = 0; s < POOL_SUB; ++s)
            acc += a.partial[(size_t)(g * POOL_SUB + s) * 128 + tid];
        p[tid] = acc / fmaxf((float)(end - start), 1.0f);
    }
    __syncthreads();
    float gi = a.b_ih[tid] + a.b_hh[tid];
    float gg = a.b_ih[512 + tid] + a.b_hh[512 + tid];
    float go = a.b_ih[768 + tid] + a.b_hh[768 + tid];
    const float4* wi = (const float4*)(a.W_ih + (size_t)tid * 128);
    const float4* wg = (const float4*)(a.W_ih + (size_t)(512 + tid) * 128);
    const float4* wo = (const float4*)(a.W_ih + (size_t)(768 + tid) * 128);
    const float4* p4 = (const float4*)p;
#pragma unroll 8
    for (int k = 0; k < 32; ++k) {
        float4 xv = p4[k];
        float4 aq = wi[k], bq = wg[k], cq = wo[k];
        gi += xv.x * aq.x + xv.y * aq.y + xv.z * aq.z + xv.w * aq.w;
        gg += xv.x * bq.x + xv.y * bq.y + xv.z * bq.z + xv.w * bq.w;
        go += xv.x * cq.x + xv.y * cq.y + xv.z * cq.z + xv.w * cq.w;
    }
    float iv = 1.f / (1.f + expf(-gi));
    float cv = iv * tanhf(gg);
    float ov = 1.f / (1.f + expf(-go));
    float hT = ov * tanhf(cv);
    redm[tid] = hT * a.Wm[tid];
    redv[tid] = hT * a.Wv[tid];
    __syncthreads();
    for (int s = 128; s > 0; s >>= 1) {
        if (tid < s) { redm[tid] += redm[tid + s]; redv[tid] += redv[tid + s]; }
        __syncthreads();
    }
    if (tid == 0) {
        a.out[g] = redm[0] + a.bm[0];
        float xv = redv[0] + a.bv[0];
        a.out[64 + g] = fmaxf(xv, 0.f) + log1pf(expf(-fabsf(xv)));  // stable softplus
    }
    __syncthreads();
}

// ---- cooperative mega-kernel ---------------------------------------------

__global__ __launch_bounds__(256, 4) void mega_kernel(MegaArgs a) {
    cg::grid_group grid = cg::this_grid();
    __shared__ __align__(16) float shraw[656];  // 2624 B
    int tid = threadIdx.x;
    int bid = blockIdx.x;
    int G = gridDim.x;
    int gstride = G * 256;
    int gtid = bid * 256 + tid;

    // P0: zero deg+cursor + W1/W2 -> bf16 transposed
    int zwords = 2 * a.N;
    for (int i = gtid; i < zwords; i += gstride) a.deg[i] = 0;
    for (int i = gtid; i < 128 * 128; i += gstride) {
        int col = i >> 7, k = i & 127;
        a.Wt1[col * 128 + k] = f2bf(a.W1[(size_t)k * 128 + col]);
        a.Wt2[col * 128 + k] = f2bf(a.W2[(size_t)k * 128 + col]);
    }
    grid.sync();

    // P1: degree count
    for (int e = gtid; e < a.E; e += gstride) atomicAdd(&a.deg[a.dst[e]], 1);
    grid.sync();

    // P2: per-chunk scan
    {
        int* s = (int*)shraw;
        for (int c = bid; c < a.nchunks; c += G) {
            int base = c * 1024;
            int v[4];
            int mysum = 0;
#pragma unroll
            for (int j = 0; j < 4; ++j) {
                int idx = base + tid * 4 + j;
                v[j] = (idx < a.N) ? a.deg[idx] : 0;
                mysum += v[j];
            }
            s[tid] = mysum;
            __syncthreads();
            for (int off = 1; off < 256; off <<= 1) {
                int t2 = (tid >= off) ? s[tid - off] : 0;
                __syncthreads();
                s[tid] += t2;
                __syncthreads();
            }
            int excl = s[tid] - mysum;
#pragma unroll
            for (int j = 0; j < 4; ++j) {
                int idx = base + tid * 4 + j;
                if (idx < a.N) a.rowptr[idx] = excl;
                excl += v[j];
            }
            if (tid == 255) a.bsums[c] = s[255];
            __syncthreads();
        }
    }
    grid.sync();

    // P3: chunk-offset fixup + dinv
    {
        int* sm = (int*)shraw;
        int* pref = sm + 64;
        if (tid < 64) sm[tid] = (tid < a.nchunks) ? a.bsums[tid] : 0;
        __syncthreads();
        if (tid == 0) {
            int s2 = 0;
            for (int i = 0; i < 64; ++i) { pref[i] = s2; s2 += sm[i]; }
            pref[64] = s2;
        }
        __syncthreads();
        for (int c = bid; c < a.nchunks; c += G) {
            int add = pref[c];
            int base = c * 1024;
#pragma unroll
            for (int j = 0; j < 4; ++j) {
                int idx = base + tid * 4 + j;
                if (idx < a.N) {
                    a.rowptr[idx] += add;
                    a.dinv[idx] = rsqrtf((float)a.deg[idx] + 1.0f);
                }
            }
        }
        if (bid == 0 && tid == 0) a.rowptr[a.N] = pref[64];
    }
    grid.sync();

    // P4: fill CSR || layer-1 GEMM
    for (int e = gtid; e < a.E; e += gstride) {
        int d = a.dst[e];
        int pos = a.rowptr[d] + atomicAdd(&a.cursor[d], 1);
        a.csr[pos] = a.src[e];
    }
    for (int t = bid; t < a.gb; t += G) gemm_tile_f32a(t, a);
    grid.sync();

    // P5: aggregate layer 1
    for (int grp = bid; grp < a.ab; grp += G) agg_group(grp, a.b1, a);
    grid.sync();

    // P6: layer-2 GEMM
    for (int t = bid; t < a.gb; t += G) gemm_tile_h(t, a);
    grid.sync();

    // P7: aggregate layer 2
    for (int grp = bid; grp < a.ab; grp += G) agg_group(grp, a.b2, a);
    grid.sync();

    // P8: pool partials (2048 units, 4 per block)
    for (int grp = bid; grp < (64 * POOL_SUB) / 4; grp += G)
        pool_partial_unit(grp * 4 + (tid >> 6), tid & 63, a);
    grid.sync();

    // P9: pool finish + LSTM + heads
    for (int g = bid; g < 64; g += G) pool_lstm_graph(g, shraw, a);
}

// ---- fallback thin kernels (proven round-13 structure) --------------------

__global__ __launch_bounds__(256) void k_p0(MegaArgs a) {
    int gtid = blockIdx.x * 256 + threadIdx.x, gstride = gridDim.x * 256;
    for (int i = gtid; i < 2 * a.N; i += gstride) a.deg[i] = 0;
    for (int i = gtid; i < 128 * 128; i += gstride) {
        int col = i >> 7, k = i & 127;
        a.Wt1[col * 128 + k] = f2bf(a.W1[(size_t)k * 128 + col]);
        a.Wt2[col * 128 + k] = f2bf(a.W2[(size_t)k * 128 + col]);
    }
}
__global__ void k_count(MegaArgs a) {
    int e = blockIdx.x * 256 + threadIdx.x;
    if (e < a.E) atomicAdd(&a.deg[a.dst[e]], 1);
}
__global__ void k_scan1(MegaArgs a) {
    __shared__ int s[256];
    int tid = threadIdx.x;
    int base = blockIdx.x * 1024;
    int v[4];
    int mysum = 0;
#pragma unroll
    for (int j = 0; j < 4; ++j) {
        int idx = base + tid * 4 + j;
        v[j] = (idx < a.N) ? a.deg[idx] : 0;
        mysum += v[j];
    }
    s[tid] = mysum;
    __syncthreads();
    for (int off = 1; off < 256; off <<= 1) {
        int t = (tid >= off) ? s[tid - off] : 0;
        __syncthreads();
        s[tid] += t;
        __syncthreads();
    }
    int excl = s[tid] - mysum;
#pragma unroll
    for (int j = 0; j < 4; ++j) {
        int idx = base + tid * 4 + j;
        if (idx < a.N) a.rowptr[idx] = excl;
        excl += v[j];
    }
    if (tid == 255) a.bsums[blockIdx.x] = s[255];
}
__global__ void k_scan23(MegaArgs a) {
    __shared__ int sm[64];
    __shared__ int pref[65];
    int tid = threadIdx.x;
    if (tid < 64) sm[tid] = (tid < a.nchunks) ? a.bsums[tid] : 0;
    __syncthreads();
    if (tid == 0) {
        int s = 0;
        for (int i = 0; i < 64; ++i) { pref[i] = s; s += sm[i]; }
        pref[64] = s;
    }
    __syncthreads();
    int add = pref[blockIdx.x];
    int base = blockIdx.x * 1024;
#pragma unroll
    for (int j = 0; j < 4; ++j) {
        int idx = base + tid * 4 + j;
        if (idx < a.N) {
            a.rowptr[idx] += add;
            a.dinv[idx] = rsqrtf((float)a.deg[idx] + 1.0f);
        }
    }
    if (blockIdx.x == 0 && tid == 0) a.rowptr[a.N] = pref[64];
}
__global__ void k_csr(MegaArgs a) {
    int e = blockIdx.x * 256 + threadIdx.x;
    if (e < a.E) {
        int d = a.dst[e];
        int pos = a.rowptr[d] + atomicAdd(&a.cursor[d], 1);
        a.csr[pos] = a.src[e];
    }
}
__global__ __launch_bounds__(256) void k_gemm1(MegaArgs a) { gemm_tile_f32a(blockIdx.x, a); }
__global__ __launch_bounds__(256) void k_gemm2(MegaArgs a) { gemm_tile_h(blockIdx.x, a); }
__global__ __launch_bounds__(256) void k_agg1(MegaArgs a) { agg_group(blockIdx.x, a.b1, a); }
__global__ __launch_bounds__(256) void k_agg2(MegaArgs a) { agg_group(blockIdx.x, a.b2, a); }
__global__ __launch_bounds__(64) void k_poolp(MegaArgs a) { pool_partial_unit(blockIdx.x, threadIdx.x, a); }
__global__ __launch_bounds__(256) void k_plstm(MegaArgs a) {
    __shared__ __align__(16) float shraw[656];
    pool_lstm_graph(blockIdx.x, shraw, a);
}

extern "C" void kernel_launch(void* const* d_in, const int* in_sizes, int n_in,
                              void* d_out, int out_size, void* d_ws, size_t ws_size,
                              hipStream_t stream) {
    MegaArgs A;
    A.x     = (const float*)d_in[0];
    const int* edge = (const int*)d_in[1];
    A.batch = (const int*)d_in[2];
    A.W1    = (const float*)d_in[3];
    A.b1    = (const float*)d_in[4];
    A.W2    = (const float*)d_in[5];
    A.b2    = (const float*)d_in[6];
    A.W_ih  = (const float*)d_in[7];
    /* d_in[8] = W_hh: dead (h0 = 0) */
    A.b_ih  = (const float*)d_in[9];
    A.b_hh  = (const float*)d_in[10];
    A.Wm    = (const float*)d_in[11];
    A.bm    = (const float*)d_in[12];
    A.Wv    = (const float*)d_in[13];
    A.bv    = (const float*)d_in[14];
    A.out   = (float*)d_out;

    const int N = in_sizes[0] / 128;
    const int E = in_sizes[1] / 2;
    A.src = edge;
    A.dst = edge + E;
    A.N = N;
    A.E = E;
    A.nchunks = (N + 1023) / 1024;  // 49 (<=64 required)
    A.gb = (N + 63) / 64;
    A.ab = (N + 3) / 4;

    char* ws = (char*)d_ws;
    size_t off = 0;
    const size_t gB = (size_t)N * 64 * sizeof(unsigned int);  // worst case (bf16)
    A.gbuf = (void*)(ws + off); off += gB;
    A.hbuf = (unsigned int*)(ws + off); off += gB;
    A.deg    = (int*)(ws + off); off += (size_t)N * sizeof(int);
    A.cursor = (int*)(ws + off); off += (size_t)N * sizeof(int);  // contiguous after deg
    A.rowptr = (int*)(ws + off); off += (size_t)(N + 1) * sizeof(int);
    off = (off + 255) & ~(size_t)255;
    A.bsums = (int*)(ws + off); off += 512;
    A.csr   = (int*)(ws + off); off += (size_t)E * sizeof(int);
    off = (off + 255) & ~(size_t)255;
    A.dinv = (float*)(ws + off); off += (size_t)N * sizeof(float);
    off = (off + 255) & ~(size_t)255;
    A.Wt1 = (unsigned short*)(ws + off); off += 128 * 128 * sizeof(unsigned short);
    A.Wt2 = (unsigned short*)(ws + off); off += 128 * 128 * sizeof(unsigned short);
    off = (off + 255) & ~(size_t)255;
    A.partial = (float*)(ws + off); off += (size_t)64 * POOL_SUB * 128 * sizeof(float);

    // --- try cooperative single-dispatch path
    hipError_t le = hipErrorUnknown;
    int dev = 0;
    if (hipGetDevice(&dev) == hipSuccess) {
        int coop = 0;
        hipDeviceGetAttribute(&coop, hipDeviceAttributeCooperativeLaunch, dev);
        int numCU = 0;
        hipDeviceGetAttribute(&numCU, hipDeviceAttributeMultiprocessorCount, dev);
        int maxB = 0;
        hipError_t oe = hipOccupancyMaxActiveBlocksPerMultiprocessor(&maxB, mega_kernel, 256, 0);
        if (coop && numCU > 0 && oe == hipSuccess && maxB > 0) {
            if (maxB > 8) maxB = 8;
            int G = numCU * maxB;
            void* kargs[] = { (void*)&A };
            le = hipLaunchCooperativeKernel((const void*)mega_kernel, dim3(G), dim3(256),
                                            kargs, 0, stream);
        }
    }
    if (le == hipSuccess) return;

    // --- fallback: proven multi-kernel pipeline (round-13 structure)
    int eb = (E + 255) / 256;
    k_p0<<<400, 256, 0, stream>>>(A);
    k_count<<<eb, 256, 0, stream>>>(A);
    k_scan1<<<A.nchunks, 256, 0, stream>>>(A);
    k_scan23<<<A.nchunks, 256, 0, stream>>>(A);
    k_csr<<<eb, 256, 0, stream>>>(A);
    k_gemm1<<<A.gb, 256, 0, stream>>>(A);
    k_agg1<<<A.ab, 256, 0, stream>>>(A);
    k_gemm2<<<A.gb, 256, 0, stream>>>(A);
    k_agg2<<<A.ab, 256, 0, stream>>>(A);
    k_poolp<<<64 * POOL_SUB, 64, 0, stream>>>(A);
    k_plstm<<<64, 256, 0, stream>>>(A);
}

// Round 16
// 205.299 us; speedup vs baseline: 3.8602x; 3.8602x over previous
//
#include <hip/hip_runtime.h>
#include <hip/hip_bf16.h>
#include <math.h>

// ---------------------------------------------------------------------------
// GCN(2 layers, fused norm) -> mean-pool -> LSTM step (h0=c0=0) -> heads
// GEMMs via bf16 MFMA (f32 accum). Gather buffer fp8-e4m3 (HW cvt), h bf16,
// all accumulation f32. Two-kernel parallel scan. 11 stream-ordered launches
// (cooperative mega-kernel measured 4-6x WORSE: grid.sync ~120us/barrier).
// ---------------------------------------------------------------------------

#define POOL_SUB 32

#if __has_builtin(__builtin_amdgcn_cvt_pk_f32_fp8) && __has_builtin(__builtin_amdgcn_cvt_pk_fp8_f32)
#define USE_FP8 1
#else
#define USE_FP8 0
#endif

typedef __attribute__((ext_vector_type(8))) short bf16x8;
typedef __attribute__((ext_vector_type(4))) float f32x4;
typedef __attribute__((ext_vector_type(2))) float f32x2;

static __device__ __forceinline__ unsigned short f2bf(float f) {
    union { float f; unsigned int u; } v; v.f = f;
    unsigned int u = v.u;
    unsigned int r = u + 0x7FFFu + ((u >> 16) & 1u);  // RNE
    return (unsigned short)(r >> 16);
}
static __device__ __forceinline__ unsigned int pack2bf(float lo, float hi) {
    return (unsigned int)f2bf(lo) | ((unsigned int)f2bf(hi) << 16);
}
static __device__ __forceinline__ float bflo(unsigned int v) {
    union { unsigned int u; float f; } w; w.u = v << 16; return w.f;
}
static __device__ __forceinline__ float bfhi(unsigned int v) {
    union { unsigned int u; float f; } w; w.u = v & 0xFFFF0000u; return w.f;
}
static __device__ __forceinline__ bf16x8 f8_to_bf(float4 f0, float4 f1) {
    union { unsigned int u[4]; bf16x8 v; } r;
    r.u[0] = pack2bf(f0.x, f0.y);
    r.u[1] = pack2bf(f0.z, f0.w);
    r.u[2] = pack2bf(f1.x, f1.y);
    r.u[3] = pack2bf(f1.z, f1.w);
    return r.v;
}
#if USE_FP8
static __device__ __forceinline__ unsigned char f2fp8(float f) {
    return (unsigned char)(__builtin_amdgcn_cvt_pk_fp8_f32(f, f, 0, false) & 0xFF);
}
#endif

// blocks [0,zb): zero deg+cursor; blocks [zb,zb+128): W1/W2 -> bf16 transposed
__global__ __launch_bounds__(256) void prep_kernel(int* __restrict__ zp, int zwords,
                                                   const float* __restrict__ W1,
                                                   const float* __restrict__ W2,
                                                   unsigned short* __restrict__ Wt1,
                                                   unsigned short* __restrict__ Wt2, int zb) {
    int b = blockIdx.x;
    int t = threadIdx.x;
    if (b < zb) {
        int i = b * 256 + t;
        if (i < zwords) zp[i] = 0;
    } else {
        int col = b - zb;  // 0..127
        if (t < 128) Wt1[col * 128 + t] = f2bf(W1[(size_t)t * 128 + col]);
        else { int k = t - 128; Wt2[col * 128 + k] = f2bf(W2[(size_t)k * 128 + col]); }
    }
}

__global__ void count_deg_kernel(const int* __restrict__ dst, int E, int* __restrict__ deg) {
    int e = blockIdx.x * blockDim.x + threadIdx.x;
    if (e < E) atomicAdd(&deg[dst[e]], 1);
}

// block scans 1024 elements (256 threads x 4)
__global__ void scan_pass1(const int* __restrict__ deg, int n,
                           int* __restrict__ rowptr, int* __restrict__ bsums) {
    __shared__ int s[256];
    int tid = threadIdx.x;
    int base = blockIdx.x * 1024;
    int v[4];
    int mysum = 0;
#pragma unroll
    for (int j = 0; j < 4; ++j) {
        int idx = base + tid * 4 + j;
        v[j] = (idx < n) ? deg[idx] : 0;
        mysum += v[j];
    }
    s[tid] = mysum;
    __syncthreads();
    for (int off = 1; off < 256; off <<= 1) {
        int t = (tid >= off) ? s[tid - off] : 0;
        __syncthreads();
        s[tid] += t;
        __syncthreads();
    }
    int excl = s[tid] - mysum;
#pragma unroll
    for (int j = 0; j < 4; ++j) {
        int idx = base + tid * 4 + j;
        if (idx < n) rowptr[idx] = excl;
        excl += v[j];
    }
    if (tid == 255) bsums[blockIdx.x] = s[255];
}

// merged pass2+3: each block redoes the tiny nb-entry prefix in LDS; also dinv.
__global__ void scan_pass23(int* __restrict__ rowptr, const int* __restrict__ bsums,
                            const int* __restrict__ deg, float* __restrict__ dinv,
                            int n, int nb) {
    __shared__ int sm[64];
    __shared__ int pref[65];
    int tid = threadIdx.x;
    if (tid < 64) sm[tid] = (tid < nb) ? bsums[tid] : 0;
    __syncthreads();
    if (tid == 0) {
        int s = 0;
#pragma unroll 8
        for (int i = 0; i < 64; ++i) { pref[i] = s; s += sm[i]; }
        pref[64] = s;
    }
    __syncthreads();
    int add = pref[blockIdx.x];
    int base = blockIdx.x * 1024;
#pragma unroll
    for (int j = 0; j < 4; ++j) {
        int idx = base + tid * 4 + j;
        if (idx < n) {
            rowptr[idx] += add;
            dinv[idx] = rsqrtf((float)deg[idx] + 1.0f);
        }
    }
    if (blockIdx.x == 0 && tid == 0) rowptr[n] = pref[64];
}

__global__ void fill_csr_kernel(const int* __restrict__ src, const int* __restrict__ dst, int E,
                                const int* __restrict__ rowptr, int* __restrict__ cursor,
                                int* __restrict__ csr) {
    int e = blockIdx.x * blockDim.x + threadIdx.x;
    if (e < E) {
        int d = dst[e];
        int pos = rowptr[d] + atomicAdd(&cursor[d], 1);
        csr[pos] = src[e];
    }
}

// ---- GEMM: out[r][c] = cvt( dinv[r] * sum_k A[r][k]*W[k][c] ), cvt = fp8/bf16
// 4 waves/block, wave: 16 rows x 128 cols, K=128 -> 32 mfma_f32_16x16x32_bf16.
// A/B same (lane,elem)->k mapping; C/D: col=lane&15, row=(lane>>4)*4+reg.

#if USE_FP8
#define G_STORE(outp, row, col, val) ((unsigned char*)(outp))[(size_t)(row) * 128 + (col)] = f2fp8(val)
#else
#define G_STORE(outp, row, col, val) ((unsigned short*)(outp))[(size_t)(row) * 128 + (col)] = f2bf(val)
#endif

// f32-input variant (layer 1): converts x to bf16 in-register.
__global__ __launch_bounds__(256) void gemm_mfma_f32a_kernel(const float* __restrict__ A,
                                                             const unsigned short* __restrict__ Wt,
                                                             const float* __restrict__ dinv,
                                                             void* __restrict__ out,
                                                             int n) {
    int tid = threadIdx.x;
    int l = tid & 63;
    int wid = tid >> 6;
    int rowbase = blockIdx.x * 64 + wid * 16;
    int lc = l & 15;
    int kq = l >> 4;

    int arow = rowbase + lc; if (arow > n - 1) arow = n - 1;
    const float* Ap = A + (size_t)arow * 128 + kq * 8;
    const unsigned short* Wp = Wt + (size_t)lc * 128 + kq * 8;

    f32x4 acc[8];
#pragma unroll
    for (int c = 0; c < 8; ++c) acc[c] = (f32x4){0.f, 0.f, 0.f, 0.f};

#pragma unroll
    for (int ks = 0; ks < 4; ++ks) {
        float4 f0 = *(const float4*)(Ap + ks * 32);
        float4 f1 = *(const float4*)(Ap + ks * 32 + 4);
        bf16x8 a = f8_to_bf(f0, f1);
#pragma unroll
        for (int c = 0; c < 8; ++c) {
            bf16x8 b = *(const bf16x8*)(Wp + c * 2048 + ks * 32);
            acc[c] = __builtin_amdgcn_mfma_f32_16x16x32_bf16(a, b, acc[c], 0, 0, 0);
        }
    }

    int r0 = kq * 4;
    float s[4];
    int orow[4];
#pragma unroll
    for (int r = 0; r < 4; ++r) {
        orow[r] = rowbase + r0 + r;
        s[r] = (orow[r] < n) ? dinv[orow[r]] : 0.f;
    }
#pragma unroll
    for (int c = 0; c < 8; ++c) {
#pragma unroll
        for (int r = 0; r < 4; ++r) {
            if (orow[r] < n) G_STORE(out, orow[r], c * 16 + lc, acc[c][r] * s[r]);
        }
    }
}

// bf16-input variant (layer 2)
__global__ __launch_bounds__(256) void gemm_mfma_kernel(const unsigned short* __restrict__ A,
                                                        const unsigned short* __restrict__ Wt,
                                                        const float* __restrict__ dinv,
                                                        void* __restrict__ out,
                                                        int n) {
    int tid = threadIdx.x;
    int l = tid & 63;
    int wid = tid >> 6;
    int rowbase = blockIdx.x * 64 + wid * 16;
    int lc = l & 15;
    int kq = l >> 4;

    int arow = rowbase + lc; if (arow > n - 1) arow = n - 1;
    const unsigned short* Ap = A + (size_t)arow * 128 + kq * 8;
    const unsigned short* Wp = Wt + (size_t)lc * 128 + kq * 8;

    f32x4 acc[8];
#pragma unroll
    for (int c = 0; c < 8; ++c) acc[c] = (f32x4){0.f, 0.f, 0.f, 0.f};

#pragma unroll
    for (int ks = 0; ks < 4; ++ks) {
        bf16x8 a = *(const bf16x8*)(Ap + ks * 32);
#pragma unroll
        for (int c = 0; c < 8; ++c) {
            bf16x8 b = *(const bf16x8*)(Wp + c * 2048 + ks * 32);
            acc[c] = __builtin_amdgcn_mfma_f32_16x16x32_bf16(a, b, acc[c], 0, 0, 0);
        }
    }

    int r0 = kq * 4;
    float s[4];
    int orow[4];
#pragma unroll
    for (int r = 0; r < 4; ++r) {
        orow[r] = rowbase + r0 + r;
        s[r] = (orow[r] < n) ? dinv[orow[r]] : 0.f;
    }
#pragma unroll
    for (int c = 0; c < 8; ++c) {
#pragma unroll
        for (int r = 0; r < 4; ++r) {
            if (orow[r] < n) G_STORE(out, orow[r], c * 16 + lc, acc[c][r] * s[r]);
        }
    }
}

// ---- aggregate: out_h[i] = bf16( relu(dinv[i]*(sum_nbr g[src] + g[i]) + bias) )
#if USE_FP8
// g fp8 rows (128 B). One wave/node: li=lane&15 owns uint2 (8 fp8 = 8 feats),
// quad=lane>>4 walks 4 neighbors/group; unrolled 2 groups (8 nbrs) in flight.
__global__ __launch_bounds__(256) void aggregate_kernel(const void* __restrict__ gv,
                                                        const int* __restrict__ rowptr,
                                                        const int* __restrict__ csr,
                                                        const float* __restrict__ dinv,
                                                        const float* __restrict__ bias,
                                                        unsigned int* __restrict__ out, int n) {
    const uint2* __restrict__ g2 = (const uint2*)gv;  // row = 16 uint2
    int lane = threadIdx.x & 63;
    int node = (blockIdx.x * blockDim.x + threadIdx.x) >> 6;
    if (node >= n) return;
    int li = lane & 15, quad = lane >> 4;
    int beg = rowptr[node], end = rowptr[node + 1];
    float a0 = 0.f, a1 = 0.f, a2 = 0.f, a3 = 0.f;
    float a4 = 0.f, a5 = 0.f, a6 = 0.f, a7 = 0.f;
    int e = beg;
    for (; e + 8 <= end; e += 8) {
        int i0 = csr[e + quad];
        int i1 = csr[e + 4 + quad];
        uint2 v = g2[(size_t)i0 * 16 + li];
        uint2 w = g2[(size_t)i1 * 16 + li];
        f32x2 p0 = __builtin_amdgcn_cvt_pk_f32_fp8(v.x, false);
        f32x2 p1 = __builtin_amdgcn_cvt_pk_f32_fp8(v.x, true);
        f32x2 p2 = __builtin_amdgcn_cvt_pk_f32_fp8(v.y, false);
        f32x2 p3 = __builtin_amdgcn_cvt_pk_f32_fp8(v.y, true);
        f32x2 q0 = __builtin_amdgcn_cvt_pk_f32_fp8(w.x, false);
        f32x2 q1 = __builtin_amdgcn_cvt_pk_f32_fp8(w.x, true);
        f32x2 q2 = __builtin_amdgcn_cvt_pk_f32_fp8(w.y, false);
        f32x2 q3 = __builtin_amdgcn_cvt_pk_f32_fp8(w.y, true);
        a0 += p0.x + q0.x; a1 += p0.y + q0.y; a2 += p1.x + q1.x; a3 += p1.y + q1.y;
        a4 += p2.x + q2.x; a5 += p2.y + q2.y; a6 += p3.x + q3.x; a7 += p3.y + q3.y;
    }
    if (e + 4 <= end) {
        uint2 v = g2[(size_t)csr[e + quad] * 16 + li];
        f32x2 p0 = __builtin_amdgcn_cvt_pk_f32_fp8(v.x, false);
        f32x2 p1 = __builtin_amdgcn_cvt_pk_f32_fp8(v.x, true);
        f32x2 p2 = __builtin_amdgcn_cvt_pk_f32_fp8(v.y, false);
        f32x2 p3 = __builtin_amdgcn_cvt_pk_f32_fp8(v.y, true);
        a0 += p0.x; a1 += p0.y; a2 += p1.x; a3 += p1.y;
        a4 += p2.x; a5 += p2.y; a6 += p3.x; a7 += p3.y;
        e += 4;
    }
    if (e + quad < end) {
        uint2 v = g2[(size_t)csr[e + quad] * 16 + li];
        f32x2 p0 = __builtin_amdgcn_cvt_pk_f32_fp8(v.x, false);
        f32x2 p1 = __builtin_amdgcn_cvt_pk_f32_fp8(v.x, true);
        f32x2 p2 = __builtin_amdgcn_cvt_pk_f32_fp8(v.y, false);
        f32x2 p3 = __builtin_amdgcn_cvt_pk_f32_fp8(v.y, true);
        a0 += p0.x; a1 += p0.y; a2 += p1.x; a3 += p1.y;
        a4 += p2.x; a5 += p2.y; a6 += p3.x; a7 += p3.y;
    }
    a0 += __shfl_xor(a0, 16, 64); a0 += __shfl_xor(a0, 32, 64);
    a1 += __shfl_xor(a1, 16, 64); a1 += __shfl_xor(a1, 32, 64);
    a2 += __shfl_xor(a2, 16, 64); a2 += __shfl_xor(a2, 32, 64);
    a3 += __shfl_xor(a3, 16, 64); a3 += __shfl_xor(a3, 32, 64);
    a4 += __shfl_xor(a4, 16, 64); a4 += __shfl_xor(a4, 32, 64);
    a5 += __shfl_xor(a5, 16, 64); a5 += __shfl_xor(a5, 32, 64);
    a6 += __shfl_xor(a6, 16, 64); a6 += __shfl_xor(a6, 32, 64);
    a7 += __shfl_xor(a7, 16, 64); a7 += __shfl_xor(a7, 32, 64);
    if (quad == 0) {
        uint2 sv = g2[(size_t)node * 16 + li];  // self loop
        f32x2 s0 = __builtin_amdgcn_cvt_pk_f32_fp8(sv.x, false);
        f32x2 s1 = __builtin_amdgcn_cvt_pk_f32_fp8(sv.x, true);
        f32x2 s2 = __builtin_amdgcn_cvt_pk_f32_fp8(sv.y, false);
        f32x2 s3 = __builtin_amdgcn_cvt_pk_f32_fp8(sv.y, true);
        float dv = dinv[node];
        float4 bl = ((const float4*)bias)[li * 2];
        float4 bh = ((const float4*)bias)[li * 2 + 1];
        float r0 = fmaxf(dv * (a0 + s0.x) + bl.x, 0.f);
        float r1 = fmaxf(dv * (a1 + s0.y) + bl.y, 0.f);
        float r2 = fmaxf(dv * (a2 + s1.x) + bl.z, 0.f);
        float r3 = fmaxf(dv * (a3 + s1.y) + bl.w, 0.f);
        float r4 = fmaxf(dv * (a4 + s2.x) + bh.x, 0.f);
        float r5 = fmaxf(dv * (a5 + s2.y) + bh.y, 0.f);
        float r6 = fmaxf(dv * (a6 + s3.x) + bh.z, 0.f);
        float r7 = fmaxf(dv * (a7 + s3.y) + bh.w, 0.f);
        uint4 o;
        o.x = pack2bf(r0, r1); o.y = pack2bf(r2, r3);
        o.z = pack2bf(r4, r5); o.w = pack2bf(r6, r7);
        ((uint4*)out)[(size_t)node * 16 + li] = o;
    }
}
#else
// bf16 fallback: li=lane&31 owns uint2 (4 feats), pair walks 2 neighbors.
__global__ __launch_bounds__(256) void aggregate_kernel(const void* __restrict__ gv,
                                                        const int* __restrict__ rowptr,
                                                        const int* __restrict__ csr,
                                                        const float* __restrict__ dinv,
                                                        const float* __restrict__ bias,
                                                        unsigned int* __restrict__ out, int n) {
    const uint2* __restrict__ g2 = (const uint2*)gv;
    int lane = threadIdx.x & 63;
    int node = (blockIdx.x * blockDim.x + threadIdx.x) >> 6;
    if (node >= n) return;
    int li = lane & 31, pair = lane >> 5;
    int beg = rowptr[node], end = rowptr[node + 1];
    float a0 = 0.f, a1 = 0.f, a2 = 0.f, a3 = 0.f;
    int e = beg;
    for (; e + 2 <= end; e += 2) {
        uint2 v = g2[(size_t)csr[e + pair] * 32 + li];
        a0 += bflo(v.x); a1 += bfhi(v.x);
        a2 += bflo(v.y); a3 += bfhi(v.y);
    }
    if (e + pair < end) {
        uint2 v = g2[(size_t)csr[e + pair] * 32 + li];
        a0 += bflo(v.x); a1 += bfhi(v.x);
        a2 += bflo(v.y); a3 += bfhi(v.y);
    }
    a0 += __shfl_xor(a0, 32, 64);
    a1 += __shfl_xor(a1, 32, 64);
    a2 += __shfl_xor(a2, 32, 64);
    a3 += __shfl_xor(a3, 32, 64);
    if (pair == 0) {
        uint2 sv = g2[(size_t)node * 32 + li];
        float dv = dinv[node];
        float4 b = ((const float4*)bias)[li];
        float r0 = fmaxf(dv * (a0 + bflo(sv.x)) + b.x, 0.f);
        float r1 = fmaxf(dv * (a1 + bfhi(sv.x)) + b.y, 0.f);
        float r2 = fmaxf(dv * (a2 + bflo(sv.y)) + b.z, 0.f);
        float r3 = fmaxf(dv * (a3 + bfhi(sv.y)) + b.w, 0.f);
        ((uint2*)out)[(size_t)node * 32 + li] = make_uint2(pack2bf(r0, r1), pack2bf(r2, r3));
    }
}
#endif

// stage 1: 64 graphs x POOL_SUB sub-blocks; 64 threads, 2 features each (bf16 in)
__global__ __launch_bounds__(64) void pool_partial_kernel(const unsigned int* __restrict__ h,
                                                          const int* __restrict__ batch, int n,
                                                          float* __restrict__ partial) {
    int g = blockIdx.x / POOL_SUB;
    int sub = blockIdx.x % POOL_SUB;
    int t = threadIdx.x;  // 0..63, packed pair t
    int lo = 0, hi = n;
    while (lo < hi) { int mid = (lo + hi) >> 1; if (batch[mid] < g) lo = mid + 1; else hi = mid; }
    int start = lo;
    hi = n;
    while (lo < hi) { int mid = (lo + hi) >> 1; if (batch[mid] < g + 1) lo = mid + 1; else hi = mid; }
    int end = lo;
    int len = end - start;
    int b0 = start + (int)((long long)len * sub / POOL_SUB);
    int b1 = start + (int)((long long)len * (sub + 1) / POOL_SUB);
    float ax = 0.f, ay = 0.f;
    int i = b0;
    for (; i + 4 <= b1; i += 4) {
        unsigned int v0 = h[(size_t)(i + 0) * 64 + t];
        unsigned int v1 = h[(size_t)(i + 1) * 64 + t];
        unsigned int v2 = h[(size_t)(i + 2) * 64 + t];
        unsigned int v3 = h[(size_t)(i + 3) * 64 + t];
        ax += bflo(v0) + bflo(v1) + bflo(v2) + bflo(v3);
        ay += bfhi(v0) + bfhi(v1) + bfhi(v2) + bfhi(v3);
    }
    for (; i < b1; ++i) {
        unsigned int v0 = h[(size_t)i * 64 + t];
        ax += bflo(v0);
        ay += bfhi(v0);
    }
    partial[(size_t)blockIdx.x * 128 + 2 * t]     = ax;
    partial[(size_t)blockIdx.x * 128 + 2 * t + 1] = ay;
}

// fused: pool finish (first 128 threads) + LSTM step + heads. 64 blocks x 256.
// gates order i,f,g,o ; f dead (c0=0), W_hh dead (h0=0).
__global__ __launch_bounds__(256) void pool_lstm_kernel(const float* __restrict__ partial,
                                                        const int* __restrict__ batch, int n,
                                                        const float* __restrict__ W_ih,
                                                        const float* __restrict__ b_ih,
                                                        const float* __restrict__ b_hh,
                                                        const float* __restrict__ Wm,
                                                        const float* __restrict__ bm,
                                                        const float* __restrict__ Wv,
                                                        const float* __restrict__ bv,
                                                        float* __restrict__ out) {
    __shared__ __align__(16) float p[128];
    __shared__ float redm[256];
    __shared__ float redv[256];
    int gph = blockIdx.x;
    int tid = threadIdx.x;
    if (tid < 128) {
        int lo = 0, hi = n;
        while (lo < hi) { int mid = (lo + hi) >> 1; if (batch[mid] < gph) lo = mid + 1; else hi = mid; }
        int start = lo;
        hi = n;
        while (lo < hi) { int mid = (lo + hi) >> 1; if (batch[mid] < gph + 1) lo = mid + 1; else hi = mid; }
        int end = lo;
        float acc = 0.f;
#pragma unroll
        for (int s = 0; s < POOL_SUB; ++s)
            acc += partial[(size_t)(gph * POOL_SUB + s) * 128 + tid];
        p[tid] = acc / fmaxf((float)(end - start), 1.0f);
    }
    __syncthreads();
    float gi = b_ih[tid] + b_hh[tid];
    float gg = b_ih[512 + tid] + b_hh[512 + tid];
    float go = b_ih[768 + tid] + b_hh[768 + tid];
    const float4* wi = (const float4*)(W_ih + (size_t)tid * 128);
    const float4* wg = (const float4*)(W_ih + (size_t)(512 + tid) * 128);
    const float4* wo = (const float4*)(W_ih + (size_t)(768 + tid) * 128);
    const float4* p4 = (const float4*)p;
#pragma unroll 8
    for (int k = 0; k < 32; ++k) {
        float4 xv = p4[k];
        float4 a = wi[k], bq = wg[k], cq = wo[k];
        gi += xv.x * a.x + xv.y * a.y + xv.z * a.z + xv.w * a.w;
        gg += xv.x * bq.x + xv.y * bq.y + xv.z * bq.z + xv.w * bq.w;
        go += xv.x * cq.x + xv.y * cq.y + xv.z * cq.z + xv.w * cq.w;
    }
    float iv = 1.f / (1.f + expf(-gi));
    float cv = iv * tanhf(gg);
    float ov = 1.f / (1.f + expf(-go));
    float hT = ov * tanhf(cv);
    redm[tid] = hT * Wm[tid];
    redv[tid] = hT * Wv[tid];
    __syncthreads();
    for (int s = 128; s > 0; s >>= 1) {
        if (tid < s) { redm[tid] += redm[tid + s]; redv[tid] += redv[tid + s]; }
        __syncthreads();
    }
    if (tid == 0) {
        out[gph] = redm[0] + bm[0];
        float xv = redv[0] + bv[0];
        out[64 + gph] = fmaxf(xv, 0.f) + log1pf(expf(-fabsf(xv)));  // stable softplus
    }
}

extern "C" void kernel_launch(void* const* d_in, const int* in_sizes, int n_in,
                              void* d_out, int out_size, void* d_ws, size_t ws_size,
                              hipStream_t stream) {
    const float* x     = (const float*)d_in[0];
    const int*   edge  = (const int*)d_in[1];
    const int*   batch = (const int*)d_in[2];
    const float* W1    = (const float*)d_in[3];
    const float* b1    = (const float*)d_in[4];
    const float* W2    = (const float*)d_in[5];
    const float* b2    = (const float*)d_in[6];
    const float* W_ih  = (const float*)d_in[7];
    /* d_in[8] = W_hh: dead (h0 = 0) */
    const float* b_ih  = (const float*)d_in[9];
    const float* b_hh  = (const float*)d_in[10];
    const float* Wm    = (const float*)d_in[11];
    const float* bm    = (const float*)d_in[12];
    const float* Wv    = (const float*)d_in[13];
    const float* bv    = (const float*)d_in[14];
    float* out = (float*)d_out;

    const int N = in_sizes[0] / 128;
    const int E = in_sizes[1] / 2;
    const int* srcIdx = edge;      // edge_index[0]
    const int* dstIdx = edge + E;  // edge_index[1]

    char* ws = (char*)d_ws;
    size_t off = 0;
    const size_t gB = (size_t)N * 64 * sizeof(unsigned int);  // worst case (bf16)
    void* gbuf = (void*)(ws + off); off += gB;
    unsigned int* hbuf = (unsigned int*)(ws + off); off += gB;
    int* deg    = (int*)(ws + off);   off += (size_t)N * sizeof(int);
    int* cursor = (int*)(ws + off);   off += (size_t)N * sizeof(int);  // adjacent to deg
    int* rowptr = (int*)(ws + off);   off += (size_t)(N + 1) * sizeof(int);
    off = (off + 255) & ~(size_t)255;
    int* bsums  = (int*)(ws + off);   off += 512;
    int* csr    = (int*)(ws + off);   off += (size_t)E * sizeof(int);
    off = (off + 255) & ~(size_t)255;
    float* dinv = (float*)(ws + off); off += (size_t)N * sizeof(float);
    off = (off + 255) & ~(size_t)255;
    unsigned short* Wt1 = (unsigned short*)(ws + off); off += 128 * 128 * sizeof(unsigned short);
    unsigned short* Wt2 = (unsigned short*)(ws + off); off += 128 * 128 * sizeof(unsigned short);
    off = (off + 255) & ~(size_t)255;
    float* partial = (float*)(ws + off); off += (size_t)64 * POOL_SUB * 128 * sizeof(float);

    // prep: zero deg+cursor and convert W1/W2 to bf16-transposed in one launch
    int zwords = 2 * N;
    int zb = (zwords + 255) / 256;
    prep_kernel<<<zb + 128, 256, 0, stream>>>(deg, zwords, W1, W2, Wt1, Wt2, zb);

    int eb = (E + 255) / 256;
    count_deg_kernel<<<eb, 256, 0, stream>>>(dstIdx, E, deg);

    int nb = (N + 1023) / 1024;  // 49 for N=50000 (<=64 required by scan)
    scan_pass1<<<nb, 256, 0, stream>>>(deg, N, rowptr, bsums);
    scan_pass23<<<nb, 256, 0, stream>>>(rowptr, bsums, deg, dinv, N, nb);
    fill_csr_kernel<<<eb, 256, 0, stream>>>(srcIdx, dstIdx, E, rowptr, cursor, csr);

    int gb = (N + 63) / 64;  // GEMM blocks (4 waves x 16 rows)
    int ab = (N + 3) / 4;    // aggregate blocks (4 nodes/block)

    // layer 1 (f32 x read directly, converted in-register)
    gemm_mfma_f32a_kernel<<<gb, 256, 0, stream>>>(x, Wt1, dinv, gbuf, N);
    aggregate_kernel<<<ab, 256, 0, stream>>>(gbuf, rowptr, csr, dinv, b1, hbuf, N);
    // layer 2
    gemm_mfma_kernel<<<gb, 256, 0, stream>>>((const unsigned short*)hbuf, Wt2, dinv, gbuf, N);
    aggregate_kernel<<<ab, 256, 0, stream>>>(gbuf, rowptr, csr, dinv, b2, hbuf, N);

    // pooling + fused finish+LSTM+heads
    pool_partial_kernel<<<64 * POOL_SUB, 64, 0, stream>>>(hbuf, batch, N, partial);
    pool_lstm_kernel<<<64, 256, 0, stream>>>(partial, batch, N, W_ih, b_ih, b_hh, Wm, bm, Wv, bv, out);
}

// Round 18
// 202.484 us; speedup vs baseline: 3.9138x; 1.0139x over previous
//
#include <hip/hip_runtime.h>
#include <hip/hip_bf16.h>
#include <math.h>

// ---------------------------------------------------------------------------
// GCN(2 layers, fused norm) -> mean-pool -> LSTM step (h0=c0=0) -> heads
// GEMMs via bf16 MFMA (f32 accum). Gather buffer fp8-e4m3 (HW cvt), h bf16,
// all accumulation f32. 10 stream-ordered launches (csr||gemm1 merged;
// cooperative mega-kernel measured 4-6x WORSE: grid.sync ~120us/barrier).
// ---------------------------------------------------------------------------

#define POOL_SUB 32

#if __has_builtin(__builtin_amdgcn_cvt_pk_f32_fp8) && __has_builtin(__builtin_amdgcn_cvt_pk_fp8_f32)
#define USE_FP8 1
#else
#define USE_FP8 0
#endif

typedef __attribute__((ext_vector_type(8))) short bf16x8;
typedef __attribute__((ext_vector_type(4))) float f32x4;
typedef __attribute__((ext_vector_type(2))) float f32x2;

static __device__ __forceinline__ unsigned short f2bf(float f) {
    union { float f; unsigned int u; } v; v.f = f;
    unsigned int u = v.u;
    unsigned int r = u + 0x7FFFu + ((u >> 16) & 1u);  // RNE
    return (unsigned short)(r >> 16);
}
static __device__ __forceinline__ unsigned int pack2bf(float lo, float hi) {
    return (unsigned int)f2bf(lo) | ((unsigned int)f2bf(hi) << 16);
}
static __device__ __forceinline__ float bflo(unsigned int v) {
    union { unsigned int u; float f; } w; w.u = v << 16; return w.f;
}
static __device__ __forceinline__ float bfhi(unsigned int v) {
    union { unsigned int u; float f; } w; w.u = v & 0xFFFF0000u; return w.f;
}
static __device__ __forceinline__ bf16x8 f8_to_bf(float4 f0, float4 f1) {
    union { unsigned int u[4]; bf16x8 v; } r;
    r.u[0] = pack2bf(f0.x, f0.y);
    r.u[1] = pack2bf(f0.z, f0.w);
    r.u[2] = pack2bf(f1.x, f1.y);
    r.u[3] = pack2bf(f1.z, f1.w);
    return r.v;
}
#if USE_FP8
static __device__ __forceinline__ unsigned char f2fp8(float f) {
    return (unsigned char)(__builtin_amdgcn_cvt_pk_fp8_f32(f, f, 0, false) & 0xFF);
}
#endif

// blocks [0,zb): zero deg+cursor; blocks [zb,zb+128): W1/W2 -> bf16 transposed
__global__ __launch_bounds__(256) void prep_kernel(int* __restrict__ zp, int zwords,
                                                   const float* __restrict__ W1,
                                                   const float* __restrict__ W2,
                                                   unsigned short* __restrict__ Wt1,
                                                   unsigned short* __restrict__ Wt2, int zb) {
    int b = blockIdx.x;
    int t = threadIdx.x;
    if (b < zb) {
        int i = b * 256 + t;
        if (i < zwords) zp[i] = 0;
    } else {
        int col = b - zb;  // 0..127
        if (t < 128) Wt1[col * 128 + t] = f2bf(W1[(size_t)t * 128 + col]);
        else { int k = t - 128; Wt2[col * 128 + k] = f2bf(W2[(size_t)k * 128 + col]); }
    }
}

__global__ void count_deg_kernel(const int* __restrict__ dst, int E, int* __restrict__ deg) {
    int e = blockIdx.x * blockDim.x + threadIdx.x;
    if (e < E) atomicAdd(&deg[dst[e]], 1);
}

// block scans 1024 elements (256 threads x 4)
__global__ void scan_pass1(const int* __restrict__ deg, int n,
                           int* __restrict__ rowptr, int* __restrict__ bsums) {
    __shared__ int s[256];
    int tid = threadIdx.x;
    int base = blockIdx.x * 1024;
    int v[4];
    int mysum = 0;
#pragma unroll
    for (int j = 0; j < 4; ++j) {
        int idx = base + tid * 4 + j;
        v[j] = (idx < n) ? deg[idx] : 0;
        mysum += v[j];
    }
    s[tid] = mysum;
    __syncthreads();
    for (int off = 1; off < 256; off <<= 1) {
        int t = (tid >= off) ? s[tid - off] : 0;
        __syncthreads();
        s[tid] += t;
        __syncthreads();
    }
    int excl = s[tid] - mysum;
#pragma unroll
    for (int j = 0; j < 4; ++j) {
        int idx = base + tid * 4 + j;
        if (idx < n) rowptr[idx] = excl;
        excl += v[j];
    }
    if (tid == 255) bsums[blockIdx.x] = s[255];
}

// merged pass2+3: each block redoes the tiny nb-entry prefix in LDS; also dinv.
__global__ void scan_pass23(int* __restrict__ rowptr, const int* __restrict__ bsums,
                            const int* __restrict__ deg, float* __restrict__ dinv,
                            int n, int nb) {
    __shared__ int sm[64];
    __shared__ int pref[65];
    int tid = threadIdx.x;
    if (tid < 64) sm[tid] = (tid < nb) ? bsums[tid] : 0;
    __syncthreads();
    if (tid == 0) {
        int s = 0;
#pragma unroll 8
        for (int i = 0; i < 64; ++i) { pref[i] = s; s += sm[i]; }
        pref[64] = s;
    }
    __syncthreads();
    int add = pref[blockIdx.x];
    int base = blockIdx.x * 1024;
#pragma unroll
    for (int j = 0; j < 4; ++j) {
        int idx = base + tid * 4 + j;
        if (idx < n) {
            rowptr[idx] += add;
            dinv[idx] = rsqrtf((float)deg[idx] + 1.0f);
        }
    }
    if (blockIdx.x == 0 && tid == 0) rowptr[n] = pref[64];
}

#if USE_FP8
#define G_STORE(outp, row, col, val) ((unsigned char*)(outp))[(size_t)(row) * 128 + (col)] = f2fp8(val)
#else
#define G_STORE(outp, row, col, val) ((unsigned short*)(outp))[(size_t)(row) * 128 + (col)] = f2bf(val)
#endif

// ---- merged: blocks [0,eb) fill CSR; blocks [eb,eb+gb) run layer-1 GEMM.
// Both depend only on scan output (rowptr/dinv/cursor) -> safe in one launch.
// GEMM: 4 waves/block, wave: 16 rows x 128 cols, K=128, mfma 16x16x32 bf16;
// A/B same (lane,elem)->k mapping; C/D: col=lane&15, row=(lane>>4)*4+reg.
__global__ __launch_bounds__(256) void csr_gemm1_kernel(const int* __restrict__ src,
                                                        const int* __restrict__ dst, int E,
                                                        const int* __restrict__ rowptr,
                                                        int* __restrict__ cursor,
                                                        int* __restrict__ csr,
                                                        const float* __restrict__ A,
                                                        const unsigned short* __restrict__ Wt,
                                                        const float* __restrict__ dinv,
                                                        void* __restrict__ out,
                                                        int n, int eb) {
    if (blockIdx.x < eb) {
        int e = blockIdx.x * 256 + threadIdx.x;
        if (e < E) {
            int d = dst[e];
            int pos = rowptr[d] + atomicAdd(&cursor[d], 1);
            csr[pos] = src[e];
        }
        return;
    }
    int tile = blockIdx.x - eb;
    int tid = threadIdx.x;
    int l = tid & 63;
    int wid = tid >> 6;
    int rowbase = tile * 64 + wid * 16;
    int lc = l & 15;
    int kq = l >> 4;

    int arow = rowbase + lc; if (arow > n - 1) arow = n - 1;
    const float* Ap = A + (size_t)arow * 128 + kq * 8;
    const unsigned short* Wp = Wt + (size_t)lc * 128 + kq * 8;

    f32x4 acc[8];
#pragma unroll
    for (int c = 0; c < 8; ++c) acc[c] = (f32x4){0.f, 0.f, 0.f, 0.f};

#pragma unroll
    for (int ks = 0; ks < 4; ++ks) {
        float4 f0 = *(const float4*)(Ap + ks * 32);
        float4 f1 = *(const float4*)(Ap + ks * 32 + 4);
        bf16x8 a = f8_to_bf(f0, f1);
#pragma unroll
        for (int c = 0; c < 8; ++c) {
            bf16x8 b = *(const bf16x8*)(Wp + c * 2048 + ks * 32);
            acc[c] = __builtin_amdgcn_mfma_f32_16x16x32_bf16(a, b, acc[c], 0, 0, 0);
        }
    }

    int r0 = kq * 4;
    float s[4];
    int orow[4];
#pragma unroll
    for (int r = 0; r < 4; ++r) {
        orow[r] = rowbase + r0 + r;
        s[r] = (orow[r] < n) ? dinv[orow[r]] : 0.f;
    }
#pragma unroll
    for (int c = 0; c < 8; ++c) {
#pragma unroll
        for (int r = 0; r < 4; ++r) {
            if (orow[r] < n) G_STORE(out, orow[r], c * 16 + lc, acc[c][r] * s[r]);
        }
    }
}

// bf16-input GEMM (layer 2)
__global__ __launch_bounds__(256) void gemm_mfma_kernel(const unsigned short* __restrict__ A,
                                                        const unsigned short* __restrict__ Wt,
                                                        const float* __restrict__ dinv,
                                                        void* __restrict__ out,
                                                        int n) {
    int tid = threadIdx.x;
    int l = tid & 63;
    int wid = tid >> 6;
    int rowbase = blockIdx.x * 64 + wid * 16;
    int lc = l & 15;
    int kq = l >> 4;

    int arow = rowbase + lc; if (arow > n - 1) arow = n - 1;
    const unsigned short* Ap = A + (size_t)arow * 128 + kq * 8;
    const unsigned short* Wp = Wt + (size_t)lc * 128 + kq * 8;

    f32x4 acc[8];
#pragma unroll
    for (int c = 0; c < 8; ++c) acc[c] = (f32x4){0.f, 0.f, 0.f, 0.f};

#pragma unroll
    for (int ks = 0; ks < 4; ++ks) {
        bf16x8 a = *(const bf16x8*)(Ap + ks * 32);
#pragma unroll
        for (int c = 0; c < 8; ++c) {
            bf16x8 b = *(const bf16x8*)(Wp + c * 2048 + ks * 32);
            acc[c] = __builtin_amdgcn_mfma_f32_16x16x32_bf16(a, b, acc[c], 0, 0, 0);
        }
    }

    int r0 = kq * 4;
    float s[4];
    int orow[4];
#pragma unroll
    for (int r = 0; r < 4; ++r) {
        orow[r] = rowbase + r0 + r;
        s[r] = (orow[r] < n) ? dinv[orow[r]] : 0.f;
    }
#pragma unroll
    for (int c = 0; c < 8; ++c) {
#pragma unroll
        for (int r = 0; r < 4; ++r) {
            if (orow[r] < n) G_STORE(out, orow[r], c * 16 + lc, acc[c][r] * s[r]);
        }
    }
}

// ---- aggregate: out_h[i] = bf16( relu(dinv[i]*(sum_nbr g[src] + g[i]) + bias) )
#if USE_FP8
// g fp8 rows (128 B). One wave/node: li=lane&15 owns uint2 (8 fp8 = 8 feats),
// quad=lane>>4 walks 4 neighbors/group; unrolled 2 groups (8 nbrs) in flight.
__global__ __launch_bounds__(256) void aggregate_kernel(const void* __restrict__ gv,
                                                        const int* __restrict__ rowptr,
                                                        const int* __restrict__ csr,
                                                        const float* __restrict__ dinv,
                                                        const float* __restrict__ bias,
                                                        unsigned int* __restrict__ out, int n) {
    const uint2* __restrict__ g2 = (const uint2*)gv;  // row = 16 uint2
    int lane = threadIdx.x & 63;
    int node = (blockIdx.x * blockDim.x + threadIdx.x) >> 6;
    if (node >= n) return;
    int li = lane & 15, quad = lane >> 4;
    int beg = rowptr[node], end = rowptr[node + 1];
    float a0 = 0.f, a1 = 0.f, a2 = 0.f, a3 = 0.f;
    float a4 = 0.f, a5 = 0.f, a6 = 0.f, a7 = 0.f;
    int e = beg;
    for (; e + 8 <= end; e += 8) {
        int i0 = csr[e + quad];
        int i1 = csr[e + 4 + quad];
        uint2 v = g2[(size_t)i0 * 16 + li];
        uint2 w = g2[(size_t)i1 * 16 + li];
        f32x2 p0 = __builtin_amdgcn_cvt_pk_f32_fp8(v.x, false);
        f32x2 p1 = __builtin_amdgcn_cvt_pk_f32_fp8(v.x, true);
        f32x2 p2 = __builtin_amdgcn_cvt_pk_f32_fp8(v.y, false);
        f32x2 p3 = __builtin_amdgcn_cvt_pk_f32_fp8(v.y, true);
        f32x2 q0 = __builtin_amdgcn_cvt_pk_f32_fp8(w.x, false);
        f32x2 q1 = __builtin_amdgcn_cvt_pk_f32_fp8(w.x, true);
        f32x2 q2 = __builtin_amdgcn_cvt_pk_f32_fp8(w.y, false);
        f32x2 q3 = __builtin_amdgcn_cvt_pk_f32_fp8(w.y, true);
        a0 += p0.x + q0.x; a1 += p0.y + q0.y; a2 += p1.x + q1.x; a3 += p1.y + q1.y;
        a4 += p2.x + q2.x; a5 += p2.y + q2.y; a6 += p3.x + q3.x; a7 += p3.y + q3.y;
    }
    if (e + 4 <= end) {
        uint2 v = g2[(size_t)csr[e + quad] * 16 + li];
        f32x2 p0 = __builtin_amdgcn_cvt_pk_f32_fp8(v.x, false);
        f32x2 p1 = __builtin_amdgcn_cvt_pk_f32_fp8(v.x, true);
        f32x2 p2 = __builtin_amdgcn_cvt_pk_f32_fp8(v.y, false);
        f32x2 p3 = __builtin_amdgcn_cvt_pk_f32_fp8(v.y, true);
        a0 += p0.x; a1 += p0.y; a2 += p1.x; a3 += p1.y;
        a4 += p2.x; a5 += p2.y; a6 += p3.x; a7 += p3.y;
        e += 4;
    }
    if (e + quad < end) {
        uint2 v = g2[(size_t)csr[e + quad] * 16 + li];
        f32x2 p0 = __builtin_amdgcn_cvt_pk_f32_fp8(v.x, false);
        f32x2 p1 = __builtin_amdgcn_cvt_pk_f32_fp8(v.x, true);
        f32x2 p2 = __builtin_amdgcn_cvt_pk_f32_fp8(v.y, false);
        f32x2 p3 = __builtin_amdgcn_cvt_pk_f32_fp8(v.y, true);
        a0 += p0.x; a1 += p0.y; a2 += p1.x; a3 += p1.y;
        a4 += p2.x; a5 += p2.y; a6 += p3.x; a7 += p3.y;
    }
    a0 += __shfl_xor(a0, 16, 64); a0 += __shfl_xor(a0, 32, 64);
    a1 += __shfl_xor(a1, 16, 64); a1 += __shfl_xor(a1, 32, 64);
    a2 += __shfl_xor(a2, 16, 64); a2 += __shfl_xor(a2, 32, 64);
    a3 += __shfl_xor(a3, 16, 64); a3 += __shfl_xor(a3, 32, 64);
    a4 += __shfl_xor(a4, 16, 64); a4 += __shfl_xor(a4, 32, 64);
    a5 += __shfl_xor(a5, 16, 64); a5 += __shfl_xor(a5, 32, 64);
    a6 += __shfl_xor(a6, 16, 64); a6 += __shfl_xor(a6, 32, 64);
    a7 += __shfl_xor(a7, 16, 64); a7 += __shfl_xor(a7, 32, 64);
    if (quad == 0) {
        uint2 sv = g2[(size_t)node * 16 + li];  // self loop
        f32x2 s0 = __builtin_amdgcn_cvt_pk_f32_fp8(sv.x, false);
        f32x2 s1 = __builtin_amdgcn_cvt_pk_f32_fp8(sv.x, true);
        f32x2 s2 = __builtin_amdgcn_cvt_pk_f32_fp8(sv.y, false);
        f32x2 s3 = __builtin_amdgcn_cvt_pk_f32_fp8(sv.y, true);
        float dv = dinv[node];
        float4 bl = ((const float4*)bias)[li * 2];
        float4 bh = ((const float4*)bias)[li * 2 + 1];
        float r0 = fmaxf(dv * (a0 + s0.x) + bl.x, 0.f);
        float r1 = fmaxf(dv * (a1 + s0.y) + bl.y, 0.f);
        float r2 = fmaxf(dv * (a2 + s1.x) + bl.z, 0.f);
        float r3 = fmaxf(dv * (a3 + s1.y) + bl.w, 0.f);
        float r4 = fmaxf(dv * (a4 + s2.x) + bh.x, 0.f);
        float r5 = fmaxf(dv * (a5 + s2.y) + bh.y, 0.f);
        float r6 = fmaxf(dv * (a6 + s3.x) + bh.z, 0.f);
        float r7 = fmaxf(dv * (a7 + s3.y) + bh.w, 0.f);
        uint4 o;
        o.x = pack2bf(r0, r1); o.y = pack2bf(r2, r3);
        o.z = pack2bf(r4, r5); o.w = pack2bf(r6, r7);
        ((uint4*)out)[(size_t)node * 16 + li] = o;
    }
}
#else
// bf16 fallback: li=lane&31 owns uint2 (4 feats), pair walks 2 neighbors.
__global__ __launch_bounds__(256) void aggregate_kernel(const void* __restrict__ gv,
                                                        const int* __restrict__ rowptr,
                                                        const int* __restrict__ csr,
                                                        const float* __restrict__ dinv,
                                                        const float* __restrict__ bias,
                                                        unsigned int* __restrict__ out, int n) {
    const uint2* __restrict__ g2 = (const uint2*)gv;
    int lane = threadIdx.x & 63;
    int node = (blockIdx.x * blockDim.x + threadIdx.x) >> 6;
    if (node >= n) return;
    int li = lane & 31, pair = lane >> 5;
    int beg = rowptr[node], end = rowptr[node + 1];
    float a0 = 0.f, a1 = 0.f, a2 = 0.f, a3 = 0.f;
    int e = beg;
    for (; e + 2 <= end; e += 2) {
        uint2 v = g2[(size_t)csr[e + pair] * 32 + li];
        a0 += bflo(v.x); a1 += bfhi(v.x);
        a2 += bflo(v.y); a3 += bfhi(v.y);
    }
    if (e + pair < end) {
        uint2 v = g2[(size_t)csr[e + pair] * 32 + li];
        a0 += bflo(v.x); a1 += bfhi(v.x);
        a2 += bflo(v.y); a3 += bfhi(v.y);
    }
    a0 += __shfl_xor(a0, 32, 64);
    a1 += __shfl_xor(a1, 32, 64);
    a2 += __shfl_xor(a2, 32, 64);
    a3 += __shfl_xor(a3, 32, 64);
    if (pair == 0) {
        uint2 sv = g2[(size_t)node * 32 + li];
        float dv = dinv[node];
        float4 b = ((const float4*)bias)[li];
        float r0 = fmaxf(dv * (a0 + bflo(sv.x)) + b.x, 0.f);
        float r1 = fmaxf(dv * (a1 + bfhi(sv.x)) + b.y, 0.f);
        float r2 = fmaxf(dv * (a2 + bflo(sv.y)) + b.z, 0.f);
        float r3 = fmaxf(dv * (a3 + bfhi(sv.y)) + b.w, 0.f);
        ((uint2*)out)[(size_t)node * 32 + li] = make_uint2(pack2bf(r0, r1), pack2bf(r2, r3));
    }
}
#endif

// stage 1: 64 graphs x POOL_SUB sub-units; 256-thread blocks, 4 units/block
// (64-thread subgroup per unit, 2 bf16 features per thread)
__global__ __launch_bounds__(256) void pool_partial_kernel(const unsigned int* __restrict__ h,
                                                           const int* __restrict__ batch, int n,
                                                           float* __restrict__ partial) {
    int unit = blockIdx.x * 4 + (threadIdx.x >> 6);
    int t = threadIdx.x & 63;
    int g = unit / POOL_SUB;
    int sub = unit % POOL_SUB;
    int lo = 0, hi = n;
    while (lo < hi) { int mid = (lo + hi) >> 1; if (batch[mid] < g) lo = mid + 1; else hi = mid; }
    int start = lo;
    hi = n;
    while (lo < hi) { int mid = (lo + hi) >> 1; if (batch[mid] < g + 1) lo = mid + 1; else hi = mid; }
    int end = lo;
    int len = end - start;
    int b0 = start + (int)((long long)len * sub / POOL_SUB);
    int b1 = start + (int)((long long)len * (sub + 1) / POOL_SUB);
    float ax = 0.f, ay = 0.f;
    int i = b0;
    for (; i + 4 <= b1; i += 4) {
        unsigned int v0 = h[(size_t)(i + 0) * 64 + t];
        unsigned int v1 = h[(size_t)(i + 1) * 64 + t];
        unsigned int v2 = h[(size_t)(i + 2) * 64 + t];
        unsigned int v3 = h[(size_t)(i + 3) * 64 + t];
        ax += bflo(v0) + bflo(v1) + bflo(v2) + bflo(v3);
        ay += bfhi(v0) + bfhi(v1) + bfhi(v2) + bfhi(v3);
    }
    for (; i < b1; ++i) {
        unsigned int v0 = h[(size_t)i * 64 + t];
        ax += bflo(v0);
        ay += bfhi(v0);
    }
    partial[(size_t)unit * 128 + 2 * t]     = ax;
    partial[(size_t)unit * 128 + 2 * t + 1] = ay;
}

// fused: pool finish (first 128 threads) + LSTM step + heads. 64 blocks x 256.
// gates order i,f,g,o ; f dead (c0=0), W_hh dead (h0=0).
__global__ __launch_bounds__(256) void pool_lstm_kernel(const float* __restrict__ partial,
                                                        const int* __restrict__ batch, int n,
                                                        const float* __restrict__ W_ih,
                                                        const float* __restrict__ b_ih,
                                                        const float* __restrict__ b_hh,
                                                        const float* __restrict__ Wm,
                                                        const float* __restrict__ bm,
                                                        const float* __restrict__ Wv,
                                                        const float* __restrict__ bv,
                                                        float* __restrict__ out) {
    __shared__ __align__(16) float p[128];
    __shared__ float redm[256];
    __shared__ float redv[256];
    int gph = blockIdx.x;
    int tid = threadIdx.x;
    if (tid < 128) {
        int lo = 0, hi = n;
        while (lo < hi) { int mid = (lo + hi) >> 1; if (batch[mid] < gph) lo = mid + 1; else hi = mid; }
        int start = lo;
        hi = n;
        while (lo < hi) { int mid = (lo + hi) >> 1; if (batch[mid] < gph + 1) lo = mid + 1; else hi = mid; }
        int end = lo;
        float acc = 0.f;
#pragma unroll
        for (int s = 0; s < POOL_SUB; ++s)
            acc += partial[(size_t)(gph * POOL_SUB + s) * 128 + tid];
        p[tid] = acc / fmaxf((float)(end - start), 1.0f);
    }
    __syncthreads();
    float gi = b_ih[tid] + b_hh[tid];
    float gg = b_ih[512 + tid] + b_hh[512 + tid];
    float go = b_ih[768 + tid] + b_hh[768 + tid];
    const float4* wi = (const float4*)(W_ih + (size_t)tid * 128);
    const float4* wg = (const float4*)(W_ih + (size_t)(512 + tid) * 128);
    const float4* wo = (const float4*)(W_ih + (size_t)(768 + tid) * 128);
    const float4* p4 = (const float4*)p;
#pragma unroll 8
    for (int k = 0; k < 32; ++k) {
        float4 xv = p4[k];
        float4 a = wi[k], bq = wg[k], cq = wo[k];
        gi += xv.x * a.x + xv.y * a.y + xv.z * a.z + xv.w * a.w;
        gg += xv.x * bq.x + xv.y * bq.y + xv.z * bq.z + xv.w * bq.w;
        go += xv.x * cq.x + xv.y * cq.y + xv.z * cq.z + xv.w * cq.w;
    }
    float iv = 1.f / (1.f + expf(-gi));
    float cv = iv * tanhf(gg);
    float ov = 1.f / (1.f + expf(-go));
    float hT = ov * tanhf(cv);
    redm[tid] = hT * Wm[tid];
    redv[tid] = hT * Wv[tid];
    __syncthreads();
    for (int s = 128; s > 0; s >>= 1) {
        if (tid < s) { redm[tid] += redm[tid + s]; redv[tid] += redv[tid + s]; }
        __syncthreads();
    }
    if (tid == 0) {
        out[gph] = redm[0] + bm[0];
        float xv = redv[0] + bv[0];
        out[64 + gph] = fmaxf(xv, 0.f) + log1pf(expf(-fabsf(xv)));  // stable softplus
    }
}

extern "C" void kernel_launch(void* const* d_in, const int* in_sizes, int n_in,
                              void* d_out, int out_size, void* d_ws, size_t ws_size,
                              hipStream_t stream) {
    const float* x     = (const float*)d_in[0];
    const int*   edge  = (const int*)d_in[1];
    const int*   batch = (const int*)d_in[2];
    const float* W1    = (const float*)d_in[3];
    const float* b1    = (const float*)d_in[4];
    const float* W2    = (const float*)d_in[5];
    const float* b2    = (const float*)d_in[6];
    const float* W_ih  = (const float*)d_in[7];
    /* d_in[8] = W_hh: dead (h0 = 0) */
    const float* b_ih  = (const float*)d_in[9];
    const float* b_hh  = (const float*)d_in[10];
    const float* Wm    = (const float*)d_in[11];
    const float* bm    = (const float*)d_in[12];
    const float* Wv    = (const float*)d_in[13];
    const float* bv    = (const float*)d_in[14];
    float* out = (float*)d_out;

    const int N = in_sizes[0] / 128;
    const int E = in_sizes[1] / 2;
    const int* srcIdx = edge;      // edge_index[0]
    const int* dstIdx = edge + E;  // edge_index[1]

    char* ws = (char*)d_ws;
    size_t off = 0;
    const size_t gB = (size_t)N * 64 * sizeof(unsigned int);  // worst case (bf16)
    void* gbuf = (void*)(ws + off); off += gB;
    unsigned int* hbuf = (unsigned int*)(ws + off); off += gB;
    int* deg    = (int*)(ws + off);   off += (size_t)N * sizeof(int);
    int* cursor = (int*)(ws + off);   off += (size_t)N * sizeof(int);  // adjacent to deg
    int* rowptr = (int*)(ws + off);   off += (size_t)(N + 1) * sizeof(int);
    off = (off + 255) & ~(size_t)255;
    int* bsums  = (int*)(ws + off);   off += 512;
    int* csr    = (int*)(ws + off);   off += (size_t)E * sizeof(int);
    off = (off + 255) & ~(size_t)255;
    float* dinv = (float*)(ws + off); off += (size_t)N * sizeof(float);
    off = (off + 255) & ~(size_t)255;
    unsigned short* Wt1 = (unsigned short*)(ws + off); off += 128 * 128 * sizeof(unsigned short);
    unsigned short* Wt2 = (unsigned short*)(ws + off); off += 128 * 128 * sizeof(unsigned short);
    off = (off + 255) & ~(size_t)255;
    float* partial = (float*)(ws + off); off += (size_t)64 * POOL_SUB * 128 * sizeof(float);

    // prep: zero deg+cursor and convert W1/W2 to bf16-transposed in one launch
    int zwords = 2 * N;
    int zb = (zwords + 255) / 256;
    prep_kernel<<<zb + 128, 256, 0, stream>>>(deg, zwords, W1, W2, Wt1, Wt2, zb);

    int eb = (E + 255) / 256;
    count_deg_kernel<<<eb, 256, 0, stream>>>(dstIdx, E, deg);

    int nb = (N + 1023) / 1024;  // 49 for N=50000 (<=64 required by scan)
    scan_pass1<<<nb, 256, 0, stream>>>(deg, N, rowptr, bsums);
    scan_pass23<<<nb, 256, 0, stream>>>(rowptr, bsums, deg, dinv, N, nb);

    int gb = (N + 63) / 64;  // GEMM blocks (4 waves x 16 rows)
    int ab = (N + 3) / 4;    // aggregate blocks (4 nodes/block)

    // CSR fill || layer-1 GEMM (independent, merged launch)
    csr_gemm1_kernel<<<eb + gb, 256, 0, stream>>>(srcIdx, dstIdx, E, rowptr, cursor, csr,
                                                  x, Wt1, dinv, gbuf, N, eb);
    aggregate_kernel<<<ab, 256, 0, stream>>>(gbuf, rowptr, csr, dinv, b1, hbuf, N);
    // layer 2
    gemm_mfma_kernel<<<gb, 256, 0, stream>>>((const unsigned short*)hbuf, Wt2, dinv, gbuf, N);
    aggregate_kernel<<<ab, 256, 0, stream>>>(gbuf, rowptr, csr, dinv, b2, hbuf, N);

    // pooling + fused finish+LSTM+heads
    pool_partial_kernel<<<(64 * POOL_SUB) / 4, 256, 0, stream>>>(hbuf, batch, N, partial);
    pool_lstm_kernel<<<64, 256, 0, stream>>>(partial, batch, N, W_ih, b_ih, b_hh, Wm, bm, Wv, bv, out);
}